// Round 8
// baseline (976.297 us; speedup 1.0000x reference)
//
#include <hip/hip_runtime.h>
#include <hip/hip_bf16.h>
#include <stdint.h>

#define NTOK 4096
#define DIM  1024
#define TOPK 128
#define GB   16      // greedy blocks (trivially co-resident on 256 CUs)
#define GT   256     // threads per greedy block; GB*GT == NTOK, 1 token/thread
#define NEGM -1e30f

// ---------------------------------------------------------------------------
// k_prep: rel[n] = ((-a[n]) - min(-a) + 1e-6) / (max(-a) - min(-a))
// ---------------------------------------------------------------------------
__global__ __launch_bounds__(1024) void k_prep(const float* __restrict__ attn,
                                               float* __restrict__ rel) {
  __shared__ float smx[16], smn[16];
  int tid = threadIdx.x;
  float mx = -3.4e38f, mn = 3.4e38f;
  for (int n = tid; n < NTOK; n += 1024) {
    float a = attn[n];
    mx = fmaxf(mx, a); mn = fminf(mn, a);
  }
  for (int o = 32; o >= 1; o >>= 1) {
    mx = fmaxf(mx, __shfl_down(mx, o, 64));
    mn = fminf(mn, __shfl_down(mn, o, 64));
  }
  if ((tid & 63) == 0) { smx[tid >> 6] = mx; smn[tid >> 6] = mn; }
  __syncthreads();
  if (tid == 0) {
    float MX = smx[0], MN = smn[0];
    for (int w = 1; w < 16; ++w) { MX = fmaxf(MX, smx[w]); MN = fminf(MN, smn[w]); }
    smx[0] = MX; smn[0] = MN;
  }
  __syncthreads();
  float amax = smx[0], amin = smn[0];
  float rmin  = -amax;               // min of (-a)
  float range = (-amin) - rmin;      // max - min
  for (int n = tid; n < NTOK; n += 1024) {
    float r = -attn[n];
    rel[n] = ((r - rmin) + 1e-6f) / range;   // same op order as numpy
  }
}

// ---------------------------------------------------------------------------
// k_norm: xn[row] = x[row] / ||x[row]||   (one block per row, fp32)
// ---------------------------------------------------------------------------
__global__ __launch_bounds__(256) void k_norm(const float* __restrict__ x,
                                              float* __restrict__ xn) {
  __shared__ float ps[4];
  int row = blockIdx.x, tid = threadIdx.x;
  const float4* xr = (const float4*)(x + (size_t)row * DIM);
  float4 v = xr[tid];                           // 256 threads * 4 = 1024 elems
  float s = v.x * v.x + v.y * v.y + v.z * v.z + v.w * v.w;
  for (int o = 32; o >= 1; o >>= 1) s += __shfl_down(s, o, 64);
  if ((tid & 63) == 0) ps[tid >> 6] = s;
  __syncthreads();
  if (tid == 0) ps[0] = ps[0] + ps[1] + ps[2] + ps[3];
  __syncthreads();
  float nrm = sqrtf(ps[0]);                      // IEEE sqrt, then IEEE divide
  float4 o4;
  o4.x = v.x / nrm; o4.y = v.y / nrm; o4.z = v.z / nrm; o4.w = v.w / nrm;
  ((float4*)(xn + (size_t)row * DIM))[tid] = o4;
}

// ---------------------------------------------------------------------------
// k_gemm: ker[i][j] = rel[i] * (xn_i . xn_j) * rel[j], fp32, symmetric.
// 128x128 tile, 8x8 microtile, BK=8 (64 FMA per 4 ds_read_b128 -> 73% FMA
// issue ratio vs r2's 57%). Per-element k-order ascending 0..1023, one FMA
// per step -> bitwise identical output to the r2 64x64 version.
// Upper tiles only. Diag tiles: full direct write (formula symmetric in
// construction). Off-diag mirror: exact (acc*relc)*relr values staged
// through a 64x68-padded LDS chunk transpose -> coalesced float4 stores.
// LDS total ~26 KB (r4's 67KB-occupancy mistake avoided).
// ---------------------------------------------------------------------------
#define GBK 8
__global__ __launch_bounds__(256) void k_gemm(const float* __restrict__ xn,
                                              const float* __restrict__ rel,
                                              float* __restrict__ ker) {
  int bi = blockIdx.y, bj = blockIdx.x;
  if (bi > bj) return;                        // symmetric: skip lower tiles
  __shared__ __align__(16) float As[GBK][132];  // [k][row]
  __shared__ __align__(16) float Bs[GBK][132];
  __shared__ __align__(16) float T[64][68];     // transpose chunk, 17.4 KB
  int tid = threadIdx.x;
  int tx = tid & 15, ty = tid >> 4;           // 16x16 threads, 8x8 micro
  int lrow = tid >> 1, lk = (tid & 1) * 4;    // 128 rows x 2 k-halves
  const float* Ag = xn + (size_t)(bi * 128 + lrow) * DIM + lk;
  const float* Bg = xn + (size_t)(bj * 128 + lrow) * DIM + lk;
  float acc[8][8] = {};
  for (int kt = 0; kt < DIM; kt += GBK) {
    float4 a4 = *(const float4*)(Ag + kt);
    float4 b4 = *(const float4*)(Bg + kt);
    __syncthreads();
    As[lk + 0][lrow] = a4.x; As[lk + 1][lrow] = a4.y;
    As[lk + 2][lrow] = a4.z; As[lk + 3][lrow] = a4.w;
    Bs[lk + 0][lrow] = b4.x; Bs[lk + 1][lrow] = b4.y;
    Bs[lk + 2][lrow] = b4.z; Bs[lk + 3][lrow] = b4.w;
    __syncthreads();
#pragma unroll
    for (int k = 0; k < GBK; ++k) {
      float4 a0 = *(const float4*)&As[k][ty * 8];
      float4 a1 = *(const float4*)&As[k][ty * 8 + 4];
      float4 b0 = *(const float4*)&Bs[k][tx * 8];
      float4 b1 = *(const float4*)&Bs[k][tx * 8 + 4];
      float ar[8] = {a0.x, a0.y, a0.z, a0.w, a1.x, a1.y, a1.z, a1.w};
      float br[8] = {b0.x, b0.y, b0.z, b0.w, b1.x, b1.y, b1.z, b1.w};
#pragma unroll
      for (int r = 0; r < 8; ++r)
#pragma unroll
        for (int c = 0; c < 8; ++c) acc[r][c] += ar[r] * br[c];
    }
  }
  float relr[8], relc[8];
#pragma unroll
  for (int r = 0; r < 8; ++r) relr[r] = rel[bi * 128 + ty * 8 + r];
#pragma unroll
  for (int c = 0; c < 8; ++c) relc[c] = rel[bj * 128 + tx * 8 + c];
  // upper half (full tile when bi==bj): K[gr][gc] = (acc*relr)*relc
#pragma unroll
  for (int r = 0; r < 8; ++r) {
    int gr = bi * 128 + ty * 8 + r;
    float4 s0, s1;
    s0.x = (acc[r][0] * relr[r]) * relc[0]; s0.y = (acc[r][1] * relr[r]) * relc[1];
    s0.z = (acc[r][2] * relr[r]) * relc[2]; s0.w = (acc[r][3] * relr[r]) * relc[3];
    s1.x = (acc[r][4] * relr[r]) * relc[4]; s1.y = (acc[r][5] * relr[r]) * relc[5];
    s1.z = (acc[r][6] * relr[r]) * relc[6]; s1.w = (acc[r][7] * relr[r]) * relc[7];
    *(float4*)&ker[(size_t)gr * NTOK + bj * 128 + tx * 8]     = s0;
    *(float4*)&ker[(size_t)gr * NTOK + bj * 128 + tx * 8 + 4] = s1;
  }
  // mirror (bi<bj): K[gc][gr] = (acc*relc)*relr via 4 chunked LDS transposes
  if (bi != bj) {
#pragma unroll
    for (int a = 0; a < 2; ++a) {
#pragma unroll
      for (int b = 0; b < 2; ++b) {
        __syncthreads();
        if ((ty >> 3) == a && (tx >> 3) == b) {
          int tyl = ty & 7, txl = tx & 7;
#pragma unroll
          for (int r = 0; r < 8; ++r)
#pragma unroll
            for (int c = 0; c < 8; ++c)
              T[txl * 8 + c][tyl * 8 + r] = (acc[r][c] * relc[c]) * relr[r];
        }
        __syncthreads();
        int u = tid >> 2, seg = (tid & 3) * 16;
        float* dst = &ker[(size_t)(bj * 128 + b * 64 + u) * NTOK +
                          bi * 128 + a * 64 + seg];
#pragma unroll
        for (int e = 0; e < 4; ++e)
          *(float4*)&dst[e * 4] = *(const float4*)&T[u][seg + e * 4];
      }
    }
  }
}

// ---------------------------------------------------------------------------
// k_greedy: 128-step greedy DPP MAP. 16 blocks x 256 threads, 1 token/thread.
// ONE barrier per iteration: it orders the per-wave argmax deposits (redw)
// AND drains the previous iteration's cis stores before tid0's RELEASE of
// this block's candidate slot. All 4 waves then poll the 16 slots
// redundantly (lanes<16), decode the winner per-wave via shuffles (no LDS,
// no barrier), and each wave loads its own colbuf copy ordered by its own
// waitcnts. History: LDS t-major histL[t][tid] (thread-private column,
// 2-way bank aliasing = free), explicitly zeroed at start.
// ---------------------------------------------------------------------------
__global__ __launch_bounds__(GT) void k_greedy(const float* __restrict__ ker,
                                               const float* __restrict__ feat,
                                               float* __restrict__ out,
                                               float* __restrict__ cis,
                                               unsigned long long* __restrict__ slots) {
  __shared__ float histL[TOPK][GT];             // [t][token], 128 KB
  __shared__ __align__(16) float colbufW[4][TOPK];  // per-wave copies, 2 KB
  __shared__ unsigned long long redw[GT / 64];
  __shared__ int selj[TOPK];
  int tid = threadIdx.x;
  int lane = tid & 63, wid = tid >> 6;
  int blk = blockIdx.x;
  int n = blk * GT + tid;                       // this thread's token
  float di2s = ker[(size_t)n * NTOK + n];       // diag of kernel
  // zero own history column (was relying on garbage*0.0 == 0 before)
#pragma unroll
  for (int t = 0; t < TOPK; ++t) histL[t][tid] = 0.f;

  for (int i = 0; i < TOPK; ++i) {
    // ---- local argmax (monotonic float->uint key, first-index tie-break)
    unsigned u = __float_as_uint(di2s);
    unsigned key = (u & 0x80000000u) ? ~u : (u | 0x80000000u);
    unsigned long long pk =
        ((unsigned long long)key << 32) | (unsigned)(NTOK - 1 - n);
    for (int o = 32; o >= 1; o >>= 1) {
      unsigned long long q = __shfl_down(pk, o, 64);
      if (q > pk) pk = q;
    }
    if (lane == 0) redw[wid] = pk;
    // ONE barrier: orders redw deposits + drains iter-(i-1) cis stores
    __syncthreads();
    if (tid == 0) {
      unsigned long long m = redw[0];
#pragma unroll
      for (int w = 1; w < GT / 64; ++w) if (redw[w] > m) m = redw[w];
      // release: publishes this block's iter-(i-1) cis stores + candidate
      __hip_atomic_store(&slots[(size_t)i * GB + blk], m, __ATOMIC_RELEASE,
                         __HIP_MEMORY_SCOPE_AGENT);
    }
    // ---- every wave polls all 16 slots (lanes 0..15), no cross-wave sync
    unsigned long long v = 0;
    if (lane < GB) {
      do {
        v = __hip_atomic_load(&slots[(size_t)i * GB + lane], __ATOMIC_RELAXED,
                              __HIP_MEMORY_SCOPE_AGENT);
      } while (v == 0);
    }
    unsigned long long b1 = v;
    for (int o = 32; o >= 1; o >>= 1) {
      unsigned long long q = __shfl_down(b1, o, 64);
      if (q > b1) b1 = q;
    }
    b1 = __shfl(b1, 0, 64);                     // broadcast within wave
    __builtin_amdgcn_fence(__ATOMIC_ACQUIRE, "agent");  // order cis/ker reads
    int j = NTOK - 1 - (int)(b1 & 0xffffffffu);
    unsigned kw = (unsigned)(b1 >> 32);
    unsigned du = (kw & 0x80000000u) ? (kw & 0x7fffffffu) : ~kw;
    float sd = sqrtf(__uint_as_float(du));      // sqrt(di2s[j]) pre-update
    if (tid == 0) selj[i] = j;
    // ---- dependent fetches, overlapped; per-wave colbuf copy (no barrier)
    float kj = ker[(size_t)j * NTOK + n];       // 1KB/block, coalesced
    {
      int t0 = lane, t1 = lane + 64;
      colbufW[wid][t0] = (t0 < i)
          ? __hip_atomic_load(&cis[(size_t)t0 * NTOK + j], __ATOMIC_RELAXED,
                              __HIP_MEMORY_SCOPE_AGENT) : 0.f;
      colbufW[wid][t1] = (t1 < i)
          ? __hip_atomic_load(&cis[(size_t)t1 * NTOK + j], __ATOMIC_RELAXED,
                              __HIP_MEMORY_SCOPE_AGENT) : 0.f;
    }
    // ---- rank-i projection: b128 colbuf broadcast + conflict-free b32 hist
    float proj = 0.f;
#pragma unroll
    for (int t = 0; t < TOPK; t += 4) {
      float4 c4 = *(const float4*)&colbufW[wid][t];
      proj += c4.x * histL[t][tid] + c4.y * histL[t + 1][tid] +
              c4.z * histL[t + 2][tid] + c4.w * histL[t + 3][tid];
    }
    float eis = (kj - proj) / sd;
    // agent-scope store: published to other XCDs by next iter's release
    __hip_atomic_store(&cis[(size_t)i * NTOK + n], eis, __ATOMIC_RELAXED,
                       __HIP_MEMORY_SCOPE_AGENT);
    histL[i][tid] = eis;                        // thread-private column write
    di2s -= eis * eis;                          // reference updates all n first,
    if (n == j) di2s = NEGM;                    // then masks j
  }
  __syncthreads();
  // ---- gather output rows: block b copies rows k = b, b+GB, ...
  for (int k = blk; k < TOPK; k += GB) {
    int j = selj[k];
    ((float4*)(out + (size_t)k * DIM))[tid] =
        ((const float4*)(feat + (size_t)j * DIM))[tid];
  }
}

// ---------------------------------------------------------------------------
// ws layout (bytes):
//   [256,16640)   128*16 u64 candidate slots (zeroed each launch)
//   [49152,65536) rel : 4096 f32
//   [65536,...)   xn  : 4096*1024 f32 (16 MB) -- reused as cis (128x4096 f32)
//                       after gemm completes (stream-ordered, xn dead then)
//   [65536+16MB)  ker : 4096*4096 f32 (64 MB)
// total ~80.1 MB
// ---------------------------------------------------------------------------
extern "C" void kernel_launch(void* const* d_in, const int* in_sizes, int n_in,
                              void* d_out, int out_size, void* d_ws, size_t ws_size,
                              hipStream_t stream) {
  const float* feat = (const float*)d_in[0];
  const float* attn = (const float*)d_in[1];
  float* out = (float*)d_out;
  char* ws = (char*)d_ws;

  unsigned long long* slots = (unsigned long long*)(ws + 256);
  float* rel = (float*)(ws + 49152);
  float* xn  = (float*)(ws + 65536);
  float* cis = xn;  // aliases xn: greedy never reads xn, gemm done first
  float* ker = (float*)(ws + 65536 + (size_t)NTOK * DIM * 4);

  hipMemsetAsync(d_ws, 0, 32768, stream);  // zero candidate slots
  k_prep<<<1, 1024, 0, stream>>>(attn, rel);
  k_norm<<<NTOK, 256, 0, stream>>>(feat, xn);
  k_gemm<<<dim3(32, 32), 256, 0, stream>>>(xn, rel, ker);
  k_greedy<<<GB, GT, 0, stream>>>(ker, feat, out, cis, slots);
}

// Round 9
// 857.800 us; speedup vs baseline: 1.1381x; 1.1381x over previous
//
#include <hip/hip_runtime.h>
#include <hip/hip_bf16.h>
#include <stdint.h>

#define NTOK 4096
#define DIM  1024
#define TOPK 128
#define GB   16      // greedy blocks (trivially co-resident on 256 CUs)
#define GT   256     // threads per greedy block; GB*GT == NTOK, 1 token/thread
#define NEGM -1e30f

// ---------------------------------------------------------------------------
// k_prep: rel[n] = ((-a[n]) - min(-a) + 1e-6) / (max(-a) - min(-a))
// ---------------------------------------------------------------------------
__global__ __launch_bounds__(1024) void k_prep(const float* __restrict__ attn,
                                               float* __restrict__ rel) {
  __shared__ float smx[16], smn[16];
  int tid = threadIdx.x;
  float mx = -3.4e38f, mn = 3.4e38f;
  for (int n = tid; n < NTOK; n += 1024) {
    float a = attn[n];
    mx = fmaxf(mx, a); mn = fminf(mn, a);
  }
  for (int o = 32; o >= 1; o >>= 1) {
    mx = fmaxf(mx, __shfl_down(mx, o, 64));
    mn = fminf(mn, __shfl_down(mn, o, 64));
  }
  if ((tid & 63) == 0) { smx[tid >> 6] = mx; smn[tid >> 6] = mn; }
  __syncthreads();
  if (tid == 0) {
    float MX = smx[0], MN = smn[0];
    for (int w = 1; w < 16; ++w) { MX = fmaxf(MX, smx[w]); MN = fminf(MN, smn[w]); }
    smx[0] = MX; smn[0] = MN;
  }
  __syncthreads();
  float amax = smx[0], amin = smn[0];
  float rmin  = -amax;               // min of (-a)
  float range = (-amin) - rmin;      // max - min
  for (int n = tid; n < NTOK; n += 1024) {
    float r = -attn[n];
    rel[n] = ((r - rmin) + 1e-6f) / range;   // same op order as numpy
  }
}

// ---------------------------------------------------------------------------
// k_norm: xn[row] = x[row] / ||x[row]||   (one block per row, fp32)
// ---------------------------------------------------------------------------
__global__ __launch_bounds__(256) void k_norm(const float* __restrict__ x,
                                              float* __restrict__ xn) {
  __shared__ float ps[4];
  int row = blockIdx.x, tid = threadIdx.x;
  const float4* xr = (const float4*)(x + (size_t)row * DIM);
  float4 v = xr[tid];                           // 256 threads * 4 = 1024 elems
  float s = v.x * v.x + v.y * v.y + v.z * v.z + v.w * v.w;
  for (int o = 32; o >= 1; o >>= 1) s += __shfl_down(s, o, 64);
  if ((tid & 63) == 0) ps[tid >> 6] = s;
  __syncthreads();
  if (tid == 0) ps[0] = ps[0] + ps[1] + ps[2] + ps[3];
  __syncthreads();
  float nrm = sqrtf(ps[0]);                      // IEEE sqrt, then IEEE divide
  float4 o4;
  o4.x = v.x / nrm; o4.y = v.y / nrm; o4.z = v.z / nrm; o4.w = v.w / nrm;
  ((float4*)(xn + (size_t)row * DIM))[tid] = o4;
}

// ---------------------------------------------------------------------------
// k_gemm: ker[i][j] = rel[i] * (xn_i . xn_j) * rel[j], fp32, symmetric.
// 128x128 tile, 8x8 microtile, BK=8, SOFTWARE-PIPELINED staging: next
// k-tile's float4 is issued before this tile's compute, so the ~900cy HBM
// latency hides under the ~1000cy FMA block (r8 exposed it serially).
// Per-element k-order ascending, one FMA per step -> bitwise-identical
// output to all prior passing versions. Upper tiles only; off-diag mirror
// via 64x68-padded LDS chunk transpose (r8-verified, coalesced stores).
// ---------------------------------------------------------------------------
#define GBK 8
__global__ __launch_bounds__(256) void k_gemm(const float* __restrict__ xn,
                                              const float* __restrict__ rel,
                                              float* __restrict__ ker) {
  int bi = blockIdx.y, bj = blockIdx.x;
  if (bi > bj) return;                        // symmetric: skip lower tiles
  __shared__ __align__(16) float As[GBK][132];  // [k][row]
  __shared__ __align__(16) float Bs[GBK][132];
  __shared__ __align__(16) float T[64][68];     // transpose chunk, 17.4 KB
  int tid = threadIdx.x;
  int tx = tid & 15, ty = tid >> 4;           // 16x16 threads, 8x8 micro
  int lrow = tid >> 1, lk = (tid & 1) * 4;    // 128 rows x 2 k-halves
  const float* Ag = xn + (size_t)(bi * 128 + lrow) * DIM + lk;
  const float* Bg = xn + (size_t)(bj * 128 + lrow) * DIM + lk;
  float acc[8][8] = {};
  float4 a4 = *(const float4*)(Ag);           // prefetch k-tile 0
  float4 b4 = *(const float4*)(Bg);
  for (int kt = 0; kt < DIM; kt += GBK) {
    __syncthreads();
    As[lk + 0][lrow] = a4.x; As[lk + 1][lrow] = a4.y;
    As[lk + 2][lrow] = a4.z; As[lk + 3][lrow] = a4.w;
    Bs[lk + 0][lrow] = b4.x; Bs[lk + 1][lrow] = b4.y;
    Bs[lk + 2][lrow] = b4.z; Bs[lk + 3][lrow] = b4.w;
    __syncthreads();
    if (kt + GBK < DIM) {                     // issue next tile; waited only
      a4 = *(const float4*)(Ag + kt + GBK);   // at next iter's LDS write
      b4 = *(const float4*)(Bg + kt + GBK);
    }
#pragma unroll
    for (int k = 0; k < GBK; ++k) {
      float4 a0 = *(const float4*)&As[k][ty * 8];
      float4 a1 = *(const float4*)&As[k][ty * 8 + 4];
      float4 b0 = *(const float4*)&Bs[k][tx * 8];
      float4 b1 = *(const float4*)&Bs[k][tx * 8 + 4];
      float ar[8] = {a0.x, a0.y, a0.z, a0.w, a1.x, a1.y, a1.z, a1.w};
      float br[8] = {b0.x, b0.y, b0.z, b0.w, b1.x, b1.y, b1.z, b1.w};
#pragma unroll
      for (int r = 0; r < 8; ++r)
#pragma unroll
        for (int c = 0; c < 8; ++c) acc[r][c] += ar[r] * br[c];
    }
  }
  float relr[8], relc[8];
#pragma unroll
  for (int r = 0; r < 8; ++r) relr[r] = rel[bi * 128 + ty * 8 + r];
#pragma unroll
  for (int c = 0; c < 8; ++c) relc[c] = rel[bj * 128 + tx * 8 + c];
  // upper half (full tile when bi==bj): K[gr][gc] = (acc*relr)*relc
#pragma unroll
  for (int r = 0; r < 8; ++r) {
    int gr = bi * 128 + ty * 8 + r;
    float4 s0, s1;
    s0.x = (acc[r][0] * relr[r]) * relc[0]; s0.y = (acc[r][1] * relr[r]) * relc[1];
    s0.z = (acc[r][2] * relr[r]) * relc[2]; s0.w = (acc[r][3] * relr[r]) * relc[3];
    s1.x = (acc[r][4] * relr[r]) * relc[4]; s1.y = (acc[r][5] * relr[r]) * relc[5];
    s1.z = (acc[r][6] * relr[r]) * relc[6]; s1.w = (acc[r][7] * relr[r]) * relc[7];
    *(float4*)&ker[(size_t)gr * NTOK + bj * 128 + tx * 8]     = s0;
    *(float4*)&ker[(size_t)gr * NTOK + bj * 128 + tx * 8 + 4] = s1;
  }
  // mirror (bi<bj): K[gc][gr] = (acc*relc)*relr via 4 chunked LDS transposes
  if (bi != bj) {
#pragma unroll
    for (int a = 0; a < 2; ++a) {
#pragma unroll
      for (int b = 0; b < 2; ++b) {
        __syncthreads();
        if ((ty >> 3) == a && (tx >> 3) == b) {
          int tyl = ty & 7, txl = tx & 7;
#pragma unroll
          for (int r = 0; r < 8; ++r)
#pragma unroll
            for (int c = 0; c < 8; ++c)
              T[txl * 8 + c][tyl * 8 + r] = (acc[r][c] * relc[c]) * relr[r];
        }
        __syncthreads();
        int u = tid >> 2, seg = (tid & 3) * 16;
        float* dst = &ker[(size_t)(bj * 128 + b * 64 + u) * NTOK +
                          bi * 128 + a * 64 + seg];
#pragma unroll
        for (int e = 0; e < 4; ++e)
          *(float4*)&dst[e * 4] = *(const float4*)&T[u][seg + e * 4];
      }
    }
  }
}

// ---------------------------------------------------------------------------
// k_greedy: 128-step greedy DPP MAP. 16 blocks x 256 threads, 1 token/thread.
// r7 structure (best measured: 454us) minus one barrier and with faster
// dependent fetches:
//  - slots padded to 64B/line (r8 showed line contention hurts)
//  - cis stored column-contiguous cisT[n][t]: winner column = one wave-wide
//    b64 load (8 lines) instead of a 128-line gather
//  - winner decoded inside wave 0 via shuffles; wave 0 loads colbuf itself
//    -> 2 barriers/iter (argmax/release + colbuf/bw publish)
//  - kj load issued BEFORE proj, consumed after -> latency hidden
// History: LDS t-major histL[t][tid] (thread-private, 2-way aliasing = free).
// ---------------------------------------------------------------------------
__global__ __launch_bounds__(GT) void k_greedy(const float* __restrict__ ker,
                                               const float* __restrict__ feat,
                                               float* __restrict__ out,
                                               float* __restrict__ cisT,
                                               unsigned long long* __restrict__ slots) {
  __shared__ float histL[TOPK][GT];             // [t][token], 128 KB
  __shared__ __align__(16) float colbuf[TOPK];
  __shared__ unsigned long long redw[GT / 64];
  __shared__ unsigned long long bwS;
  __shared__ int selj[TOPK];
  int tid = threadIdx.x;
  int lane = tid & 63, wid = tid >> 6;
  int blk = blockIdx.x;
  int n = blk * GT + tid;                       // this thread's token
  float di2s = ker[(size_t)n * NTOK + n];       // diag of kernel
#pragma unroll
  for (int t = 0; t < TOPK; ++t) histL[t][tid] = 0.f;  // zero own column

  for (int i = 0; i < TOPK; ++i) {
    // ---- local argmax (monotonic float->uint key, first-index tie-break)
    unsigned u = __float_as_uint(di2s);
    unsigned key = (u & 0x80000000u) ? ~u : (u | 0x80000000u);
    unsigned long long pk =
        ((unsigned long long)key << 32) | (unsigned)(NTOK - 1 - n);
    for (int o = 32; o >= 1; o >>= 1) {
      unsigned long long q = __shfl_down(pk, o, 64);
      if (q > pk) pk = q;
    }
    if (lane == 0) redw[wid] = pk;
    __syncthreads();   // B1: orders redw + drains iter-(i-1) cisT stores
    if (tid == 0) {
      unsigned long long m = redw[0];
#pragma unroll
      for (int w = 1; w < GT / 64; ++w) if (redw[w] > m) m = redw[w];
      // release: publishes this block's iter-(i-1) cisT stores + candidate
      __hip_atomic_store(&slots[((size_t)i * GB + blk) * 8], m,
                         __ATOMIC_RELEASE, __HIP_MEMORY_SCOPE_AGENT);
    }
    if (wid == 0) {
      // ---- wave 0: poll 16 padded slots (lanes 0..15)
      unsigned long long v = 0;
      if (lane < GB) {
        do {
          v = __hip_atomic_load(&slots[((size_t)i * GB + lane) * 8],
                                __ATOMIC_RELAXED, __HIP_MEMORY_SCOPE_AGENT);
        } while (v == 0);
      }
      unsigned long long b1 = v;
      for (int o = 32; o >= 1; o >>= 1) {
        unsigned long long q = __shfl_down(b1, o, 64);
        if (q > b1) b1 = q;
      }
      b1 = __shfl(b1, 0, 64);                   // broadcast winner in-wave
      __builtin_amdgcn_fence(__ATOMIC_ACQUIRE, "agent");  // order cisT reads
      int jw = NTOK - 1 - (int)(b1 & 0xffffffffu);
      // winner's cis column: 128 contiguous floats, 64 lanes x b64
      unsigned long long cu = __hip_atomic_load(
          (const unsigned long long*)(cisT + (size_t)jw * TOPK) + lane,
          __ATOMIC_RELAXED, __HIP_MEMORY_SCOPE_AGENT);
      union { unsigned long long u64; float f[2]; } cc; cc.u64 = cu;
      colbuf[lane * 2]     = cc.f[0];           // rows t>=i are finite garbage
      colbuf[lane * 2 + 1] = cc.f[1];           // (x0 via zeroed histL)
      if (lane == 0) bwS = b1;
    }
    __syncthreads();   // B2: colbuf + bwS published block-wide
    unsigned long long b1 = bwS;
    int j = NTOK - 1 - (int)(b1 & 0xffffffffu);
    unsigned kw = (unsigned)(b1 >> 32);
    unsigned du = (kw & 0x80000000u) ? (kw & 0x7fffffffu) : ~kw;
    float sd = sqrtf(__uint_as_float(du));      // sqrt(di2s[j]) pre-update
    if (tid == 0) selj[i] = j;
    // ---- kj issued now, consumed after proj -> latency hidden under proj
    float kj = ker[(size_t)j * NTOK + n];       // 1KB/block, coalesced, IC-hot
    float proj = 0.f;
#pragma unroll
    for (int t = 0; t < TOPK; t += 4) {
      float4 c4 = *(const float4*)&colbuf[t];
      proj += c4.x * histL[t][tid] + c4.y * histL[t + 1][tid] +
              c4.z * histL[t + 2][tid] + c4.w * histL[t + 3][tid];
    }
    float eis = (kj - proj) / sd;
    // column-contiguous store; published by next iter's release
    __hip_atomic_store(&cisT[(size_t)n * TOPK + i], eis, __ATOMIC_RELAXED,
                       __HIP_MEMORY_SCOPE_AGENT);
    histL[i][tid] = eis;                        // thread-private column write
    di2s -= eis * eis;                          // reference updates all n first,
    if (n == j) di2s = NEGM;                    // then masks j
  }
  __syncthreads();
  // ---- gather output rows: block b copies rows k = b, b+GB, ...
  for (int k = blk; k < TOPK; k += GB) {
    int j = selj[k];
    ((float4*)(out + (size_t)k * DIM))[tid] =
        ((const float4*)(feat + (size_t)j * DIM))[tid];
  }
}

// ---------------------------------------------------------------------------
// ws layout (bytes):
//   [0,131072)      128*16 u64 slots, padded to 64B/slot (zeroed each launch)
//   [131072,147456) rel : 4096 f32
//   [1MB,...)       xn  : 4096*1024 f32 (16 MB) -- first 2MB reused as
//                   cisT (4096x128 f32) after gemm (stream-ordered)
//   [1MB+16MB,...)  ker : 4096*4096 f32 (64 MB)
// total ~81 MB
// ---------------------------------------------------------------------------
extern "C" void kernel_launch(void* const* d_in, const int* in_sizes, int n_in,
                              void* d_out, int out_size, void* d_ws, size_t ws_size,
                              hipStream_t stream) {
  const float* feat = (const float*)d_in[0];
  const float* attn = (const float*)d_in[1];
  float* out = (float*)d_out;
  char* ws = (char*)d_ws;

  unsigned long long* slots = (unsigned long long*)ws;
  float* rel  = (float*)(ws + 131072);
  float* xn   = (float*)(ws + (1 << 20));
  float* cisT = xn;  // aliases xn: greedy never reads xn, gemm done first
  float* ker  = (float*)(ws + (1 << 20) + (size_t)NTOK * DIM * 4);

  hipMemsetAsync(d_ws, 0, 131072, stream);  // zero padded slots
  k_prep<<<1, 1024, 0, stream>>>(attn, rel);
  k_norm<<<NTOK, 256, 0, stream>>>(feat, xn);
  k_gemm<<<dim3(32, 32), 256, 0, stream>>>(xn, rel, ker);
  k_greedy<<<GB, GT, 0, stream>>>(ker, feat, out, cisT, slots);
}

// Round 10
// 705.632 us; speedup vs baseline: 1.3836x; 1.2156x over previous
//
#include <hip/hip_runtime.h>
#include <hip/hip_bf16.h>
#include <stdint.h>

#define NTOK 4096
#define DIM  1024
#define TOPK 128
#define GB   16      // greedy blocks
#define GT   256     // threads per greedy block; GB*GT == NTOK
#define NEGM -1e30f

typedef __attribute__((ext_vector_type(8))) short bf16x8;
typedef __attribute__((ext_vector_type(4))) float f32x4;

// ---------------------------------------------------------------------------
// k_prep: rel[n] = ((-a[n]) - min(-a) + 1e-6) / (max(-a) - min(-a))
// ---------------------------------------------------------------------------
__global__ __launch_bounds__(1024) void k_prep(const float* __restrict__ attn,
                                               float* __restrict__ rel) {
  __shared__ float smx[16], smn[16];
  int tid = threadIdx.x;
  float mx = -3.4e38f, mn = 3.4e38f;
  for (int n = tid; n < NTOK; n += 1024) {
    float a = attn[n];
    mx = fmaxf(mx, a); mn = fminf(mn, a);
  }
  for (int o = 32; o >= 1; o >>= 1) {
    mx = fmaxf(mx, __shfl_down(mx, o, 64));
    mn = fminf(mn, __shfl_down(mn, o, 64));
  }
  if ((tid & 63) == 0) { smx[tid >> 6] = mx; smn[tid >> 6] = mn; }
  __syncthreads();
  if (tid == 0) {
    float MX = smx[0], MN = smn[0];
    for (int w = 1; w < 16; ++w) { MX = fmaxf(MX, smx[w]); MN = fminf(MN, smn[w]); }
    smx[0] = MX; smn[0] = MN;
  }
  __syncthreads();
  float amax = smx[0], amin = smn[0];
  float rmin  = -amax;
  float range = (-amin) - rmin;
  for (int n = tid; n < NTOK; n += 1024) {
    float r = -attn[n];
    rel[n] = ((r - rmin) + 1e-6f) / range;
  }
}

// ---------------------------------------------------------------------------
// k_norm: xn = x/||x||, then EXACT bf16 split: hi=bf16(xn), lo=bf16(xn-hi).
// H,L row-major [4096][1024] bf16. (xn fp32 no longer materialized.)
// ---------------------------------------------------------------------------
__global__ __launch_bounds__(256) void k_norm(const float* __restrict__ x,
                                              __hip_bfloat16* __restrict__ H,
                                              __hip_bfloat16* __restrict__ L) {
  __shared__ float ps[4];
  int row = blockIdx.x, tid = threadIdx.x;
  const float4* xr = (const float4*)(x + (size_t)row * DIM);
  float4 v = xr[tid];
  float s = v.x * v.x + v.y * v.y + v.z * v.z + v.w * v.w;
  for (int o = 32; o >= 1; o >>= 1) s += __shfl_down(s, o, 64);
  if ((tid & 63) == 0) ps[tid >> 6] = s;
  __syncthreads();
  if (tid == 0) ps[0] = ps[0] + ps[1] + ps[2] + ps[3];
  __syncthreads();
  float nrm = sqrtf(ps[0]);
  float xf[4] = {v.x / nrm, v.y / nrm, v.z / nrm, v.w / nrm};
  __hip_bfloat16 hh[4], ll[4];
#pragma unroll
  for (int e = 0; e < 4; ++e) {
    hh[e] = __float2bfloat16(xf[e]);
    float lof = xf[e] - __bfloat162float(hh[e]);
    ll[e] = __float2bfloat16(lof);
  }
  *(short4*)(H + (size_t)row * DIM + tid * 4) = *(short4*)hh;
  *(short4*)(L + (size_t)row * DIM + tid * 4) = *(short4*)ll;
}

// ---------------------------------------------------------------------------
// k_gemm (MFMA split-bf16): sim = hh+hl+lh+ll as one K=4096 bf16 GEMM over
// phases (H,H),(H,L),(L,H),(L,L); ker = (sim*rel_row)*rel_col.
// 128x128 tile, 4 waves (2x2), 16x16x32 MFMA, 4x4 acc tiles/wave, BK=64,
// software-pipelined staging. Upper tiles only; mirror tiles are BITWISE
// equal (same k-order, commutative exact products) -> mirror written via
// per-wave LDS transpose of the rel-scaled values, coalesced float4 stores.
// LDS 36.9 KB (staging; reused for transpose after K-loop).
// Fragment maps (m89/m120-verified): A[m=lane&15][k=quad*8+j],
// B[k=quad*8+j][n=lane&15], C/D row=(lane>>4)*4+e, col=lane&15.
// ---------------------------------------------------------------------------
#define GBK 64
__global__ __launch_bounds__(256) void k_gemm(const __hip_bfloat16* __restrict__ H,
                                              const __hip_bfloat16* __restrict__ L,
                                              const float* __restrict__ rel,
                                              float* __restrict__ ker) {
  int bi = blockIdx.y, bj = blockIdx.x;
  if (bi > bj) return;                        // symmetric: upper tiles only
  __shared__ __align__(16) char smem[36864];  // As [0,18432), Bs [18432,36864)
  int tid = threadIdx.x;
  int lane = tid & 63, wid = tid >> 6;
  int wr = wid >> 1, wc = wid & 1;
  int lm = lane & 15, quad = lane >> 4;
  const __hip_bfloat16* PA[4] = {H, H, L, L};
  const __hip_bfloat16* PB[4] = {H, L, H, L};
  int lr = tid >> 1;                          // staging row 0..127
  int lg = (tid & 1) * 32;                    // staging col offset (bf16)
  f32x4 acc[4][4];
#pragma unroll
  for (int r = 0; r < 4; ++r)
#pragma unroll
    for (int c = 0; c < 4; ++c) acc[r][c] = (f32x4){0.f, 0.f, 0.f, 0.f};
  bf16x8 pa[4], pb[4];
  {
    const __hip_bfloat16* ag = PA[0] + (size_t)(bi * 128 + lr) * DIM + lg;
    const __hip_bfloat16* bg = PB[0] + (size_t)(bj * 128 + lr) * DIM + lg;
#pragma unroll
    for (int j = 0; j < 4; ++j) {
      pa[j] = *(const bf16x8*)(ag + j * 8);
      pb[j] = *(const bf16x8*)(bg + j * 8);
    }
  }
  for (int kt = 0; kt < 4096; kt += GBK) {    // virtual K = 4*1024
    __syncthreads();
#pragma unroll
    for (int j = 0; j < 4; ++j) {             // stride 72 bf16 = 144 B
      *(bf16x8*)(smem + lr * 144 + lg * 2 + j * 16) = pa[j];
      *(bf16x8*)(smem + 18432 + lr * 144 + lg * 2 + j * 16) = pb[j];
    }
    __syncthreads();
    int kn = kt + GBK;
    if (kn < 4096) {                          // prefetch next stage
      int p = kn >> 10, kk = kn & 1023;
      const __hip_bfloat16* ag = PA[p] + (size_t)(bi * 128 + lr) * DIM + kk + lg;
      const __hip_bfloat16* bg = PB[p] + (size_t)(bj * 128 + lr) * DIM + kk + lg;
#pragma unroll
      for (int j = 0; j < 4; ++j) {
        pa[j] = *(const bf16x8*)(ag + j * 8);
        pb[j] = *(const bf16x8*)(bg + j * 8);
      }
    }
#pragma unroll
    for (int kq = 0; kq < GBK; kq += 32) {
      bf16x8 af[4], bff[4];
#pragma unroll
      for (int r = 0; r < 4; ++r)
        af[r] = *(const bf16x8*)(smem + (wr * 64 + r * 16 + lm) * 144 +
                                 (kq + quad * 8) * 2);
#pragma unroll
      for (int c = 0; c < 4; ++c)
        bff[c] = *(const bf16x8*)(smem + 18432 + (wc * 64 + c * 16 + lm) * 144 +
                                  (kq + quad * 8) * 2);
#pragma unroll
      for (int r = 0; r < 4; ++r)
#pragma unroll
        for (int c = 0; c < 4; ++c)
          acc[r][c] = __builtin_amdgcn_mfma_f32_16x16x32_bf16(
              af[r], bff[c], acc[r][c], 0, 0, 0);
    }
  }
  // ---- epilogue: rel scaling, reference op order (sim*rel_row)*rel_col
  float rr[16], rc[4];
#pragma unroll
  for (int r = 0; r < 4; ++r)
#pragma unroll
    for (int e = 0; e < 4; ++e)
      rr[r * 4 + e] = rel[bi * 128 + wr * 64 + r * 16 + quad * 4 + e];
#pragma unroll
  for (int c = 0; c < 4; ++c) rc[c] = rel[bj * 128 + wc * 64 + c * 16 + lm];
#pragma unroll
  for (int r = 0; r < 4; ++r) {
    int grow = bi * 128 + wr * 64 + r * 16 + quad * 4;
#pragma unroll
    for (int c = 0; c < 4; ++c) {
      int gcol = bj * 128 + wc * 64 + c * 16 + lm;
#pragma unroll
      for (int e = 0; e < 4; ++e)
        ker[(size_t)(grow + e) * NTOK + gcol] =
            (acc[r][c][e] * rr[r * 4 + e]) * rc[c];
    }
  }
  // ---- mirror (bi<bj): ker[gc][gr] = (sim*rel_gc)*rel_gr, LDS transpose
  if (bi != bj) {
    __syncthreads();                          // staging reads done; reuse smem
    float* Tw = (float*)(smem + wid * 4672);  // per-wave [16][73] fp32
#pragma unroll
    for (int c = 0; c < 4; ++c) {
#pragma unroll
      for (int r = 0; r < 4; ++r)
#pragma unroll
        for (int e = 0; e < 4; ++e)
          Tw[lm * 73 + r * 16 + quad * 4 + e] =
              (acc[r][c][e] * rc[c]) * rr[r * 4 + e];
      __syncthreads();                        // write->read (cross-lane) order
      int cc2 = lane >> 2, seg = lane & 3;
      float* dst = &ker[(size_t)(bj * 128 + wc * 64 + c * 16 + cc2) * NTOK +
                        bi * 128 + wr * 64 + seg * 16];
#pragma unroll
      for (int e = 0; e < 4; ++e)
        *(float4*)&dst[e * 4] = *(const float4*)&Tw[cc2 * 73 + seg * 16 + e * 4];
      __syncthreads();                        // before next pass overwrites Tw
    }
  }
}

// ---------------------------------------------------------------------------
// k_greedy: UNCHANGED from r9 (measured floor ~454us across 3 structures).
// ---------------------------------------------------------------------------
__global__ __launch_bounds__(GT) void k_greedy(const float* __restrict__ ker,
                                               const float* __restrict__ feat,
                                               float* __restrict__ out,
                                               float* __restrict__ cisT,
                                               unsigned long long* __restrict__ slots) {
  __shared__ float histL[TOPK][GT];             // [t][token], 128 KB
  __shared__ __align__(16) float colbuf[TOPK];
  __shared__ unsigned long long redw[GT / 64];
  __shared__ unsigned long long bwS;
  __shared__ int selj[TOPK];
  int tid = threadIdx.x;
  int lane = tid & 63, wid = tid >> 6;
  int blk = blockIdx.x;
  int n = blk * GT + tid;
  float di2s = ker[(size_t)n * NTOK + n];
#pragma unroll
  for (int t = 0; t < TOPK; ++t) histL[t][tid] = 0.f;

  for (int i = 0; i < TOPK; ++i) {
    unsigned u = __float_as_uint(di2s);
    unsigned key = (u & 0x80000000u) ? ~u : (u | 0x80000000u);
    unsigned long long pk =
        ((unsigned long long)key << 32) | (unsigned)(NTOK - 1 - n);
    for (int o = 32; o >= 1; o >>= 1) {
      unsigned long long q = __shfl_down(pk, o, 64);
      if (q > pk) pk = q;
    }
    if (lane == 0) redw[wid] = pk;
    __syncthreads();   // B1: orders redw + drains iter-(i-1) cisT stores
    if (tid == 0) {
      unsigned long long m = redw[0];
#pragma unroll
      for (int w = 1; w < GT / 64; ++w) if (redw[w] > m) m = redw[w];
      __hip_atomic_store(&slots[((size_t)i * GB + blk) * 8], m,
                         __ATOMIC_RELEASE, __HIP_MEMORY_SCOPE_AGENT);
    }
    if (wid == 0) {
      unsigned long long v = 0;
      if (lane < GB) {
        do {
          v = __hip_atomic_load(&slots[((size_t)i * GB + lane) * 8],
                                __ATOMIC_RELAXED, __HIP_MEMORY_SCOPE_AGENT);
        } while (v == 0);
      }
      unsigned long long b1 = v;
      for (int o = 32; o >= 1; o >>= 1) {
        unsigned long long q = __shfl_down(b1, o, 64);
        if (q > b1) b1 = q;
      }
      b1 = __shfl(b1, 0, 64);
      __builtin_amdgcn_fence(__ATOMIC_ACQUIRE, "agent");
      int jw = NTOK - 1 - (int)(b1 & 0xffffffffu);
      unsigned long long cu = __hip_atomic_load(
          (const unsigned long long*)(cisT + (size_t)jw * TOPK) + lane,
          __ATOMIC_RELAXED, __HIP_MEMORY_SCOPE_AGENT);
      union { unsigned long long u64; float f[2]; } cc; cc.u64 = cu;
      colbuf[lane * 2]     = cc.f[0];
      colbuf[lane * 2 + 1] = cc.f[1];
      if (lane == 0) bwS = b1;
    }
    __syncthreads();   // B2: colbuf + bwS published block-wide
    unsigned long long b1 = bwS;
    int j = NTOK - 1 - (int)(b1 & 0xffffffffu);
    unsigned kw = (unsigned)(b1 >> 32);
    unsigned du = (kw & 0x80000000u) ? (kw & 0x7fffffffu) : ~kw;
    float sd = sqrtf(__uint_as_float(du));
    if (tid == 0) selj[i] = j;
    float kj = ker[(size_t)j * NTOK + n];
    float proj = 0.f;
#pragma unroll
    for (int t = 0; t < TOPK; t += 4) {
      float4 c4 = *(const float4*)&colbuf[t];
      proj += c4.x * histL[t][tid] + c4.y * histL[t + 1][tid] +
              c4.z * histL[t + 2][tid] + c4.w * histL[t + 3][tid];
    }
    float eis = (kj - proj) / sd;
    __hip_atomic_store(&cisT[(size_t)n * TOPK + i], eis, __ATOMIC_RELAXED,
                       __HIP_MEMORY_SCOPE_AGENT);
    histL[i][tid] = eis;
    di2s -= eis * eis;
    if (n == j) di2s = NEGM;
  }
  __syncthreads();
  for (int k = blk; k < TOPK; k += GB) {
    int j = selj[k];
    ((float4*)(out + (size_t)k * DIM))[tid] =
        ((const float4*)(feat + (size_t)j * DIM))[tid];
  }
}

// ---------------------------------------------------------------------------
// ws layout (bytes):
//   [0,131072)        slots (64B-padded, zeroed each launch)
//   [131072,147456)   rel  : 4096 f32
//   [1MB, +8MB)       H    : 4096x1024 bf16
//   [9MB+1MB, +8MB)   L    : 4096x1024 bf16   (at 1MB+8MB)
//   [17MB+1MB, +2MB)  cisT : 4096x128 f32
//   [20MB+1MB, +64MB) ker  : 4096x4096 f32
// total ~85 MB
// ---------------------------------------------------------------------------
extern "C" void kernel_launch(void* const* d_in, const int* in_sizes, int n_in,
                              void* d_out, int out_size, void* d_ws, size_t ws_size,
                              hipStream_t stream) {
  const float* feat = (const float*)d_in[0];
  const float* attn = (const float*)d_in[1];
  float* out = (float*)d_out;
  char* ws = (char*)d_ws;

  unsigned long long* slots = (unsigned long long*)ws;
  float* rel = (float*)(ws + 131072);
  __hip_bfloat16* H = (__hip_bfloat16*)(ws + (1 << 20));
  __hip_bfloat16* L = (__hip_bfloat16*)(ws + (1 << 20) + (8 << 20));
  float* cisT = (float*)(ws + (1 << 20) + (16 << 20));
  float* ker  = (float*)(ws + (1 << 20) + (16 << 20) + (4 << 20));

  hipMemsetAsync(d_ws, 0, 131072, stream);
  k_prep<<<1, 1024, 0, stream>>>(attn, rel);
  k_norm<<<NTOK, 256, 0, stream>>>(feat, H, L);
  k_gemm<<<dim3(32, 32), 256, 0, stream>>>(H, L, rel, ker);
  k_greedy<<<GB, GT, 0, stream>>>(ker, feat, out, cisT, slots);
}

// Round 11
// 656.409 us; speedup vs baseline: 1.4873x; 1.0750x over previous
//
#include <hip/hip_runtime.h>
#include <hip/hip_bf16.h>
#include <stdint.h>

#define NTOK 4096
#define DIM  1024
#define TOPK 128
#define GB   32      // greedy blocks (r3-proven 32-slot exchange)
#define GT   128     // threads per greedy block; GB*GT == NTOK
#define NEGM -1e30f

typedef __attribute__((ext_vector_type(8))) short bf16x8;
typedef __attribute__((ext_vector_type(4))) float f32x4;

// ---------------------------------------------------------------------------
// k_prep: rel[n] = ((-a[n]) - min(-a) + 1e-6) / (max(-a) - min(-a))
// ---------------------------------------------------------------------------
__global__ __launch_bounds__(1024) void k_prep(const float* __restrict__ attn,
                                               float* __restrict__ rel) {
  __shared__ float smx[16], smn[16];
  int tid = threadIdx.x;
  float mx = -3.4e38f, mn = 3.4e38f;
  for (int n = tid; n < NTOK; n += 1024) {
    float a = attn[n];
    mx = fmaxf(mx, a); mn = fminf(mn, a);
  }
  for (int o = 32; o >= 1; o >>= 1) {
    mx = fmaxf(mx, __shfl_down(mx, o, 64));
    mn = fminf(mn, __shfl_down(mn, o, 64));
  }
  if ((tid & 63) == 0) { smx[tid >> 6] = mx; smn[tid >> 6] = mn; }
  __syncthreads();
  if (tid == 0) {
    float MX = smx[0], MN = smn[0];
    for (int w = 1; w < 16; ++w) { MX = fmaxf(MX, smx[w]); MN = fminf(MN, smn[w]); }
    smx[0] = MX; smn[0] = MN;
  }
  __syncthreads();
  float amax = smx[0], amin = smn[0];
  float rmin  = -amax;
  float range = (-amin) - rmin;
  for (int n = tid; n < NTOK; n += 1024) {
    float r = -attn[n];
    rel[n] = ((r - rmin) + 1e-6f) / range;
  }
}

// ---------------------------------------------------------------------------
// k_norm: xn = x/||x||, then EXACT bf16 split: hi=bf16(xn), lo=bf16(xn-hi).
// ---------------------------------------------------------------------------
__global__ __launch_bounds__(256) void k_norm(const float* __restrict__ x,
                                              __hip_bfloat16* __restrict__ H,
                                              __hip_bfloat16* __restrict__ L) {
  __shared__ float ps[4];
  int row = blockIdx.x, tid = threadIdx.x;
  const float4* xr = (const float4*)(x + (size_t)row * DIM);
  float4 v = xr[tid];
  float s = v.x * v.x + v.y * v.y + v.z * v.z + v.w * v.w;
  for (int o = 32; o >= 1; o >>= 1) s += __shfl_down(s, o, 64);
  if ((tid & 63) == 0) ps[tid >> 6] = s;
  __syncthreads();
  if (tid == 0) ps[0] = ps[0] + ps[1] + ps[2] + ps[3];
  __syncthreads();
  float nrm = sqrtf(ps[0]);
  float xf[4] = {v.x / nrm, v.y / nrm, v.z / nrm, v.w / nrm};
  __hip_bfloat16 hh[4], ll[4];
#pragma unroll
  for (int e = 0; e < 4; ++e) {
    hh[e] = __float2bfloat16(xf[e]);
    float lof = xf[e] - __bfloat162float(hh[e]);
    ll[e] = __float2bfloat16(lof);
  }
  *(short4*)(H + (size_t)row * DIM + tid * 4) = *(short4*)hh;
  *(short4*)(L + (size_t)row * DIM + tid * 4) = *(short4*)ll;
}

// ---------------------------------------------------------------------------
// k_gemm (MFMA split-bf16): UNCHANGED from r10 (measured ~206us, exact).
// ---------------------------------------------------------------------------
#define GBK 64
__global__ __launch_bounds__(256) void k_gemm(const __hip_bfloat16* __restrict__ H,
                                              const __hip_bfloat16* __restrict__ L,
                                              const float* __restrict__ rel,
                                              float* __restrict__ ker) {
  int bi = blockIdx.y, bj = blockIdx.x;
  if (bi > bj) return;
  __shared__ __align__(16) char smem[36864];
  int tid = threadIdx.x;
  int lane = tid & 63, wid = tid >> 6;
  int wr = wid >> 1, wc = wid & 1;
  int lm = lane & 15, quad = lane >> 4;
  const __hip_bfloat16* PA[4] = {H, H, L, L};
  const __hip_bfloat16* PB[4] = {H, L, H, L};
  int lr = tid >> 1;
  int lg = (tid & 1) * 32;
  f32x4 acc[4][4];
#pragma unroll
  for (int r = 0; r < 4; ++r)
#pragma unroll
    for (int c = 0; c < 4; ++c) acc[r][c] = (f32x4){0.f, 0.f, 0.f, 0.f};
  bf16x8 pa[4], pb[4];
  {
    const __hip_bfloat16* ag = PA[0] + (size_t)(bi * 128 + lr) * DIM + lg;
    const __hip_bfloat16* bg = PB[0] + (size_t)(bj * 128 + lr) * DIM + lg;
#pragma unroll
    for (int j = 0; j < 4; ++j) {
      pa[j] = *(const bf16x8*)(ag + j * 8);
      pb[j] = *(const bf16x8*)(bg + j * 8);
    }
  }
  for (int kt = 0; kt < 4096; kt += GBK) {
    __syncthreads();
#pragma unroll
    for (int j = 0; j < 4; ++j) {
      *(bf16x8*)(smem + lr * 144 + lg * 2 + j * 16) = pa[j];
      *(bf16x8*)(smem + 18432 + lr * 144 + lg * 2 + j * 16) = pb[j];
    }
    __syncthreads();
    int kn = kt + GBK;
    if (kn < 4096) {
      int p = kn >> 10, kk = kn & 1023;
      const __hip_bfloat16* ag = PA[p] + (size_t)(bi * 128 + lr) * DIM + kk + lg;
      const __hip_bfloat16* bg = PB[p] + (size_t)(bj * 128 + lr) * DIM + kk + lg;
#pragma unroll
      for (int j = 0; j < 4; ++j) {
        pa[j] = *(const bf16x8*)(ag + j * 8);
        pb[j] = *(const bf16x8*)(bg + j * 8);
      }
    }
#pragma unroll
    for (int kq = 0; kq < GBK; kq += 32) {
      bf16x8 af[4], bff[4];
#pragma unroll
      for (int r = 0; r < 4; ++r)
        af[r] = *(const bf16x8*)(smem + (wr * 64 + r * 16 + lm) * 144 +
                                 (kq + quad * 8) * 2);
#pragma unroll
      for (int c = 0; c < 4; ++c)
        bff[c] = *(const bf16x8*)(smem + 18432 + (wc * 64 + c * 16 + lm) * 144 +
                                  (kq + quad * 8) * 2);
#pragma unroll
      for (int r = 0; r < 4; ++r)
#pragma unroll
        for (int c = 0; c < 4; ++c)
          acc[r][c] = __builtin_amdgcn_mfma_f32_16x16x32_bf16(
              af[r], bff[c], acc[r][c], 0, 0, 0);
    }
  }
  float rr[16], rc[4];
#pragma unroll
  for (int r = 0; r < 4; ++r)
#pragma unroll
    for (int e = 0; e < 4; ++e)
      rr[r * 4 + e] = rel[bi * 128 + wr * 64 + r * 16 + quad * 4 + e];
#pragma unroll
  for (int c = 0; c < 4; ++c) rc[c] = rel[bj * 128 + wc * 64 + c * 16 + lm];
#pragma unroll
  for (int r = 0; r < 4; ++r) {
    int grow = bi * 128 + wr * 64 + r * 16 + quad * 4;
#pragma unroll
    for (int c = 0; c < 4; ++c) {
      int gcol = bj * 128 + wc * 64 + c * 16 + lm;
#pragma unroll
      for (int e = 0; e < 4; ++e)
        ker[(size_t)(grow + e) * NTOK + gcol] =
            (acc[r][c][e] * rr[r * 4 + e]) * rc[c];
    }
  }
  if (bi != bj) {
    __syncthreads();
    float* Tw = (float*)(smem + wid * 4672);
#pragma unroll
    for (int c = 0; c < 4; ++c) {
#pragma unroll
      for (int r = 0; r < 4; ++r)
#pragma unroll
        for (int e = 0; e < 4; ++e)
          Tw[lm * 73 + r * 16 + quad * 4 + e] =
              (acc[r][c][e] * rc[c]) * rr[r * 4 + e];
      __syncthreads();
      int cc2 = lane >> 2, seg = lane & 3;
      float* dst = &ker[(size_t)(bj * 128 + wc * 64 + c * 16 + cc2) * NTOK +
                        bi * 128 + wr * 64 + seg * 16];
#pragma unroll
      for (int e = 0; e < 4; ++e)
        *(float4*)&dst[e * 4] = *(const float4*)&Tw[cc2 * 73 + seg * 16 + e * 4];
      __syncthreads();
    }
  }
}

// ---------------------------------------------------------------------------
// k_greedy: 32 blocks x 128 threads, 1 token/thread. r9 exchange skeleton.
// LDS-traffic fix (the real 3.55us/iter term): hist is token-major
// histT[token][132] -> wave-wide ds_read_b128, stride 132%32==4 gives each
// bank exactly 2 words/quarter-wave = conflict-free; proj loop bound is
// dynamic (t<i, round-up quad; overshoot terms are exact +-0 via zeroed
// histT and cannot propagate: (kj - proj) identical for +-0 proj).
// Per-CU LDS per iter: 2 waves x ~32 b128 ~= 780cy ~= 0.33us (was 1.9).
// ---------------------------------------------------------------------------
__global__ __launch_bounds__(GT) void k_greedy(const float* __restrict__ ker,
                                               const float* __restrict__ feat,
                                               float* __restrict__ out,
                                               float* __restrict__ cisT,
                                               unsigned long long* __restrict__ slots) {
  __shared__ __align__(16) float histT[GT][132];   // [token][t], 67.6 KB
  __shared__ __align__(16) float colbuf[TOPK];
  __shared__ unsigned long long redw[GT / 64];
  __shared__ unsigned long long bwS;
  __shared__ int selj[TOPK];
  int tid = threadIdx.x;
  int lane = tid & 63, wid = tid >> 6;
  int blk = blockIdx.x;
  int n = blk * GT + tid;
  float di2s = ker[(size_t)n * NTOK + n];
#pragma unroll
  for (int t = 0; t < TOPK; t += 4)                // b128, conflict-free
    *(float4*)&histT[tid][t] = (float4){0.f, 0.f, 0.f, 0.f};

  for (int i = 0; i < TOPK; ++i) {
    // ---- local argmax (monotonic key, first-index tie-break)
    unsigned u = __float_as_uint(di2s);
    unsigned key = (u & 0x80000000u) ? ~u : (u | 0x80000000u);
    unsigned long long pk =
        ((unsigned long long)key << 32) | (unsigned)(NTOK - 1 - n);
    for (int o = 32; o >= 1; o >>= 1) {
      unsigned long long q = __shfl_down(pk, o, 64);
      if (q > pk) pk = q;
    }
    if (lane == 0) redw[wid] = pk;
    __syncthreads();   // B1: orders redw + drains iter-(i-1) cisT stores
    if (tid == 0) {
      unsigned long long m = redw[0];
      if (redw[1] > m) m = redw[1];
      __hip_atomic_store(&slots[((size_t)i * GB + blk) * 8], m,
                         __ATOMIC_RELEASE, __HIP_MEMORY_SCOPE_AGENT);
    }
    if (wid == 0) {
      // ---- wave 0: poll 32 padded slots (lanes 0..31)
      unsigned long long v = 0;
      if (lane < GB) {
        do {
          v = __hip_atomic_load(&slots[((size_t)i * GB + lane) * 8],
                                __ATOMIC_RELAXED, __HIP_MEMORY_SCOPE_AGENT);
        } while (v == 0);
      }
      unsigned long long b1 = v;
      for (int o = 32; o >= 1; o >>= 1) {
        unsigned long long q = __shfl_down(b1, o, 64);
        if (q > b1) b1 = q;
      }
      b1 = __shfl(b1, 0, 64);
      __builtin_amdgcn_fence(__ATOMIC_ACQUIRE, "agent");
      int jw = NTOK - 1 - (int)(b1 & 0xffffffffu);
      unsigned long long cu = __hip_atomic_load(
          (const unsigned long long*)(cisT + (size_t)jw * TOPK) + lane,
          __ATOMIC_RELAXED, __HIP_MEMORY_SCOPE_AGENT);
      union { unsigned long long u64; float f[2]; } cc; cc.u64 = cu;
      colbuf[lane * 2]     = cc.f[0];
      colbuf[lane * 2 + 1] = cc.f[1];
      if (lane == 0) bwS = b1;
    }
    __syncthreads();   // B2: colbuf + bwS published block-wide
    unsigned long long b1 = bwS;
    int j = NTOK - 1 - (int)(b1 & 0xffffffffu);
    unsigned kw = (unsigned)(b1 >> 32);
    unsigned du = (kw & 0x80000000u) ? (kw & 0x7fffffffu) : ~kw;
    float sd = sqrtf(__uint_as_float(du));
    if (tid == 0) selj[i] = j;
    // ---- kj issued before proj, consumed after -> latency hidden
    float kj = ker[(size_t)j * NTOK + n];
    float proj = 0.f;
    for (int t = 0; t < i; t += 4) {           // dynamic bound: avg 16 quads
      float4 c4 = *(const float4*)&colbuf[t];
      float4 h4 = *(const float4*)&histT[tid][t];
      proj += c4.x * h4.x + c4.y * h4.y + c4.z * h4.z + c4.w * h4.w;
    }
    float eis = (kj - proj) / sd;
    __hip_atomic_store(&cisT[(size_t)n * TOPK + i], eis, __ATOMIC_RELAXED,
                       __HIP_MEMORY_SCOPE_AGENT);
    histT[tid][i] = eis;
    di2s -= eis * eis;
    if (n == j) di2s = NEGM;
  }
  __syncthreads();
  // ---- gather output rows: block b copies rows k = b, b+GB, ...
  for (int k = blk; k < TOPK; k += GB) {
    int j = selj[k];
    const float4* src = (const float4*)(feat + (size_t)j * DIM);
    float4* dst = (float4*)(out + (size_t)k * DIM);
    dst[tid]       = src[tid];
    dst[tid + GT]  = src[tid + GT];
  }
}

// ---------------------------------------------------------------------------
// ws layout (bytes):
//   [0,262144)        slots: 128 iters x 32 blocks x 64B (zeroed each launch)
//   [262144,278528)   rel  : 4096 f32
//   [1MB, +8MB)       H    : 4096x1024 bf16
//   [1MB+8MB, +8MB)   L    : 4096x1024 bf16
//   [1MB+16MB, +2MB)  cisT : 4096x128 f32
//   [1MB+20MB, +64MB) ker  : 4096x4096 f32
// total ~85 MB
// ---------------------------------------------------------------------------
extern "C" void kernel_launch(void* const* d_in, const int* in_sizes, int n_in,
                              void* d_out, int out_size, void* d_ws, size_t ws_size,
                              hipStream_t stream) {
  const float* feat = (const float*)d_in[0];
  const float* attn = (const float*)d_in[1];
  float* out = (float*)d_out;
  char* ws = (char*)d_ws;

  unsigned long long* slots = (unsigned long long*)ws;
  float* rel = (float*)(ws + 262144);
  __hip_bfloat16* H = (__hip_bfloat16*)(ws + (1 << 20));
  __hip_bfloat16* L = (__hip_bfloat16*)(ws + (1 << 20) + (8 << 20));
  float* cisT = (float*)(ws + (1 << 20) + (16 << 20));
  float* ker  = (float*)(ws + (1 << 20) + (16 << 20) + (4 << 20));

  hipMemsetAsync(d_ws, 0, 262144, stream);
  k_prep<<<1, 1024, 0, stream>>>(attn, rel);
  k_norm<<<NTOK, 256, 0, stream>>>(feat, H, L);
  k_gemm<<<dim3(32, 32), 256, 0, stream>>>(H, L, rel, ker);
  k_greedy<<<GB, GT, 0, stream>>>(ker, feat, out, cisT, slots);
}

// Round 12
// 638.233 us; speedup vs baseline: 1.5297x; 1.0285x over previous
//
#include <hip/hip_runtime.h>
#include <hip/hip_bf16.h>
#include <stdint.h>

#define NTOK 4096
#define DIM  1024
#define TOPK 128
#define GB   32      // greedy blocks
#define GT   128     // threads per greedy block; GB*GT == NTOK
#define NEGM -1e30f

typedef __attribute__((ext_vector_type(8))) short bf16x8;
typedef __attribute__((ext_vector_type(4))) float f32x4;

// ---------------------------------------------------------------------------
// k_prep: rel[n] = ((-a[n]) - min(-a) + 1e-6) / (max(-a) - min(-a))
// ---------------------------------------------------------------------------
__global__ __launch_bounds__(1024) void k_prep(const float* __restrict__ attn,
                                               float* __restrict__ rel) {
  __shared__ float smx[16], smn[16];
  int tid = threadIdx.x;
  float mx = -3.4e38f, mn = 3.4e38f;
  for (int n = tid; n < NTOK; n += 1024) {
    float a = attn[n];
    mx = fmaxf(mx, a); mn = fminf(mn, a);
  }
  for (int o = 32; o >= 1; o >>= 1) {
    mx = fmaxf(mx, __shfl_down(mx, o, 64));
    mn = fminf(mn, __shfl_down(mn, o, 64));
  }
  if ((tid & 63) == 0) { smx[tid >> 6] = mx; smn[tid >> 6] = mn; }
  __syncthreads();
  if (tid == 0) {
    float MX = smx[0], MN = smn[0];
    for (int w = 1; w < 16; ++w) { MX = fmaxf(MX, smx[w]); MN = fminf(MN, smn[w]); }
    smx[0] = MX; smn[0] = MN;
  }
  __syncthreads();
  float amax = smx[0], amin = smn[0];
  float rmin  = -amax;
  float range = (-amin) - rmin;
  for (int n = tid; n < NTOK; n += 1024) {
    float r = -attn[n];
    rel[n] = ((r - rmin) + 1e-6f) / range;
  }
}

// ---------------------------------------------------------------------------
// k_norm: xn = x/||x||, then EXACT bf16 split: hi=bf16(xn), lo=bf16(xn-hi).
// ---------------------------------------------------------------------------
__global__ __launch_bounds__(256) void k_norm(const float* __restrict__ x,
                                              __hip_bfloat16* __restrict__ H,
                                              __hip_bfloat16* __restrict__ L) {
  __shared__ float ps[4];
  int row = blockIdx.x, tid = threadIdx.x;
  const float4* xr = (const float4*)(x + (size_t)row * DIM);
  float4 v = xr[tid];
  float s = v.x * v.x + v.y * v.y + v.z * v.z + v.w * v.w;
  for (int o = 32; o >= 1; o >>= 1) s += __shfl_down(s, o, 64);
  if ((tid & 63) == 0) ps[tid >> 6] = s;
  __syncthreads();
  if (tid == 0) ps[0] = ps[0] + ps[1] + ps[2] + ps[3];
  __syncthreads();
  float nrm = sqrtf(ps[0]);
  float xf[4] = {v.x / nrm, v.y / nrm, v.z / nrm, v.w / nrm};
  __hip_bfloat16 hh[4], ll[4];
#pragma unroll
  for (int e = 0; e < 4; ++e) {
    hh[e] = __float2bfloat16(xf[e]);
    float lof = xf[e] - __bfloat162float(hh[e]);
    ll[e] = __float2bfloat16(lof);
  }
  *(short4*)(H + (size_t)row * DIM + tid * 4) = *(short4*)hh;
  *(short4*)(L + (size_t)row * DIM + tid * 4) = *(short4*)ll;
}

// ---------------------------------------------------------------------------
// k_gemm (MFMA split-bf16): same math/order as r10/r11 (ker bitwise equal);
// staging rewritten m97-style: __builtin_amdgcn_global_load_lds width=16,
// single 32KB buffer, 2 barriers/stage. No padding allowed (LDS dest is
// wave-uniform base + lane*16) -> XOR-swizzled chunks:
//   chunk(row,kc) = row*8 + (kc ^ (row&7)), 16B chunks (8 bf16)
// Staging identity: issue (wid,q), lane l covers row=wid*32+q*8+(l>>3),
// kc=(l&7)^((l>>3)&7) -> chunk idx == (wid*4+q)*64 + l  (lane-linear ✓).
// Fragment b128 reads: banks spread 8 ways, 2-way lane aliasing = free.
// ---------------------------------------------------------------------------
#define GBK 64
__global__ __launch_bounds__(256) void k_gemm(const __hip_bfloat16* __restrict__ H,
                                              const __hip_bfloat16* __restrict__ L,
                                              const float* __restrict__ rel,
                                              float* __restrict__ ker) {
  int bi = blockIdx.y, bj = blockIdx.x;
  if (bi > bj) return;
  __shared__ __align__(16) char smem[36864];  // A [0,16K), B [16K,32K) swizzled
  int tid = threadIdx.x;
  int lane = tid & 63, wid = tid >> 6;
  int wr = wid >> 1, wc = wid & 1;
  int lm = lane & 15, quad = lane >> 4;
  const __hip_bfloat16* PA[4] = {H, H, L, L};
  const __hip_bfloat16* PB[4] = {H, L, H, L};
  int srow = wid * 32 + (lane >> 3);          // staging row (+ q*8 per issue)
  int kcs  = (lane & 7) ^ ((lane >> 3) & 7);  // swizzled k-chunk to fetch
  f32x4 acc[4][4];
#pragma unroll
  for (int r = 0; r < 4; ++r)
#pragma unroll
    for (int c = 0; c < 4; ++c) acc[r][c] = (f32x4){0.f, 0.f, 0.f, 0.f};

  for (int kt = 0; kt < 4096; kt += GBK) {    // virtual K = 4 phases x 1024
    int p = kt >> 10, kk = kt & 1023;
    const __hip_bfloat16* Ab = PA[p] + (size_t)(bi * 128) * DIM + kk;
    const __hip_bfloat16* Bb = PB[p] + (size_t)(bj * 128) * DIM + kk;
    __syncthreads();                          // prev compute done with LDS
#pragma unroll
    for (int q = 0; q < 4; ++q) {
      const __hip_bfloat16* ga = Ab + (size_t)(srow + q * 8) * DIM + kcs * 8;
      const __hip_bfloat16* gb = Bb + (size_t)(srow + q * 8) * DIM + kcs * 8;
      __builtin_amdgcn_global_load_lds(
          (const __attribute__((address_space(1))) void*)ga,
          (__attribute__((address_space(3))) void*)(smem + (wid * 4 + q) * 1024),
          16, 0, 0);
      __builtin_amdgcn_global_load_lds(
          (const __attribute__((address_space(1))) void*)gb,
          (__attribute__((address_space(3))) void*)(smem + 16384 +
                                                    (wid * 4 + q) * 1024),
          16, 0, 0);
    }
    __syncthreads();                          // vmcnt(0) drain -> LDS ready
#pragma unroll
    for (int kq = 0; kq < 2; ++kq) {          // k halves of 32
      int kc = kq * 4 + quad;
      bf16x8 af[4], bff[4];
#pragma unroll
      for (int r = 0; r < 4; ++r) {
        int row = wr * 64 + r * 16 + lm;
        af[r] = *(const bf16x8*)(smem + row * 128 + ((kc ^ (lm & 7)) * 16));
      }
#pragma unroll
      for (int c = 0; c < 4; ++c) {
        int row = wc * 64 + c * 16 + lm;
        bff[c] = *(const bf16x8*)(smem + 16384 + row * 128 +
                                  ((kc ^ (lm & 7)) * 16));
      }
#pragma unroll
      for (int r = 0; r < 4; ++r)
#pragma unroll
        for (int c = 0; c < 4; ++c)
          acc[r][c] = __builtin_amdgcn_mfma_f32_16x16x32_bf16(
              af[r], bff[c], acc[r][c], 0, 0, 0);
    }
  }
  // ---- epilogue: rel scaling, reference op order (unchanged from r10)
  float rr[16], rc[4];
#pragma unroll
  for (int r = 0; r < 4; ++r)
#pragma unroll
    for (int e = 0; e < 4; ++e)
      rr[r * 4 + e] = rel[bi * 128 + wr * 64 + r * 16 + quad * 4 + e];
#pragma unroll
  for (int c = 0; c < 4; ++c) rc[c] = rel[bj * 128 + wc * 64 + c * 16 + lm];
#pragma unroll
  for (int r = 0; r < 4; ++r) {
    int grow = bi * 128 + wr * 64 + r * 16 + quad * 4;
#pragma unroll
    for (int c = 0; c < 4; ++c) {
      int gcol = bj * 128 + wc * 64 + c * 16 + lm;
#pragma unroll
      for (int e = 0; e < 4; ++e)
        ker[(size_t)(grow + e) * NTOK + gcol] =
            (acc[r][c][e] * rr[r * 4 + e]) * rc[c];
    }
  }
  if (bi != bj) {
    __syncthreads();
    float* Tw = (float*)(smem + wid * 4672);
#pragma unroll
    for (int c = 0; c < 4; ++c) {
#pragma unroll
      for (int r = 0; r < 4; ++r)
#pragma unroll
        for (int e = 0; e < 4; ++e)
          Tw[lm * 73 + r * 16 + quad * 4 + e] =
              (acc[r][c][e] * rc[c]) * rr[r * 4 + e];
      __syncthreads();
      int cc2 = lane >> 2, seg = lane & 3;
      float* dst = &ker[(size_t)(bj * 128 + wc * 64 + c * 16 + cc2) * NTOK +
                        bi * 128 + wr * 64 + seg * 16];
#pragma unroll
      for (int e = 0; e < 4; ++e)
        *(float4*)&dst[e * 4] = *(const float4*)&Tw[cc2 * 73 + seg * 16 + e * 4];
      __syncthreads();
    }
  }
}

// ---------------------------------------------------------------------------
// k_greedy: UNCHANGED from r11 (408us; exchange-RT-bound, frozen).
// ---------------------------------------------------------------------------
__global__ __launch_bounds__(GT) void k_greedy(const float* __restrict__ ker,
                                               const float* __restrict__ feat,
                                               float* __restrict__ out,
                                               float* __restrict__ cisT,
                                               unsigned long long* __restrict__ slots) {
  __shared__ __align__(16) float histT[GT][132];   // [token][t], 67.6 KB
  __shared__ __align__(16) float colbuf[TOPK];
  __shared__ unsigned long long redw[GT / 64];
  __shared__ unsigned long long bwS;
  __shared__ int selj[TOPK];
  int tid = threadIdx.x;
  int lane = tid & 63, wid = tid >> 6;
  int blk = blockIdx.x;
  int n = blk * GT + tid;
  float di2s = ker[(size_t)n * NTOK + n];
#pragma unroll
  for (int t = 0; t < TOPK; t += 4)
    *(float4*)&histT[tid][t] = (float4){0.f, 0.f, 0.f, 0.f};

  for (int i = 0; i < TOPK; ++i) {
    unsigned u = __float_as_uint(di2s);
    unsigned key = (u & 0x80000000u) ? ~u : (u | 0x80000000u);
    unsigned long long pk =
        ((unsigned long long)key << 32) | (unsigned)(NTOK - 1 - n);
    for (int o = 32; o >= 1; o >>= 1) {
      unsigned long long q = __shfl_down(pk, o, 64);
      if (q > pk) pk = q;
    }
    if (lane == 0) redw[wid] = pk;
    __syncthreads();   // B1: orders redw + drains iter-(i-1) cisT stores
    if (tid == 0) {
      unsigned long long m = redw[0];
      if (redw[1] > m) m = redw[1];
      __hip_atomic_store(&slots[((size_t)i * GB + blk) * 8], m,
                         __ATOMIC_RELEASE, __HIP_MEMORY_SCOPE_AGENT);
    }
    if (wid == 0) {
      unsigned long long v = 0;
      if (lane < GB) {
        do {
          v = __hip_atomic_load(&slots[((size_t)i * GB + lane) * 8],
                                __ATOMIC_RELAXED, __HIP_MEMORY_SCOPE_AGENT);
        } while (v == 0);
      }
      unsigned long long b1 = v;
      for (int o = 32; o >= 1; o >>= 1) {
        unsigned long long q = __shfl_down(b1, o, 64);
        if (q > b1) b1 = q;
      }
      b1 = __shfl(b1, 0, 64);
      __builtin_amdgcn_fence(__ATOMIC_ACQUIRE, "agent");
      int jw = NTOK - 1 - (int)(b1 & 0xffffffffu);
      unsigned long long cu = __hip_atomic_load(
          (const unsigned long long*)(cisT + (size_t)jw * TOPK) + lane,
          __ATOMIC_RELAXED, __HIP_MEMORY_SCOPE_AGENT);
      union { unsigned long long u64; float f[2]; } cc; cc.u64 = cu;
      colbuf[lane * 2]     = cc.f[0];
      colbuf[lane * 2 + 1] = cc.f[1];
      if (lane == 0) bwS = b1;
    }
    __syncthreads();   // B2: colbuf + bwS published block-wide
    unsigned long long b1 = bwS;
    int j = NTOK - 1 - (int)(b1 & 0xffffffffu);
    unsigned kw = (unsigned)(b1 >> 32);
    unsigned du = (kw & 0x80000000u) ? (kw & 0x7fffffffu) : ~kw;
    float sd = sqrtf(__uint_as_float(du));
    if (tid == 0) selj[i] = j;
    float kj = ker[(size_t)j * NTOK + n];
    float proj = 0.f;
    for (int t = 0; t < i; t += 4) {
      float4 c4 = *(const float4*)&colbuf[t];
      float4 h4 = *(const float4*)&histT[tid][t];
      proj += c4.x * h4.x + c4.y * h4.y + c4.z * h4.z + c4.w * h4.w;
    }
    float eis = (kj - proj) / sd;
    __hip_atomic_store(&cisT[(size_t)n * TOPK + i], eis, __ATOMIC_RELAXED,
                       __HIP_MEMORY_SCOPE_AGENT);
    histT[tid][i] = eis;
    di2s -= eis * eis;
    if (n == j) di2s = NEGM;
  }
  __syncthreads();
  for (int k = blk; k < TOPK; k += GB) {
    int j = selj[k];
    const float4* src = (const float4*)(feat + (size_t)j * DIM);
    float4* dst = (float4*)(out + (size_t)k * DIM);
    dst[tid]       = src[tid];
    dst[tid + GT]  = src[tid + GT];
  }
}

// ---------------------------------------------------------------------------
// ws layout (bytes):
//   [0,262144)        slots: 128 iters x 32 blocks x 64B (zeroed each launch)
//   [262144,278528)   rel  : 4096 f32
//   [1MB, +8MB)       H    : 4096x1024 bf16
//   [1MB+8MB, +8MB)   L    : 4096x1024 bf16
//   [1MB+16MB, +2MB)  cisT : 4096x128 f32
//   [1MB+20MB, +64MB) ker  : 4096x4096 f32
// total ~85 MB
// ---------------------------------------------------------------------------
extern "C" void kernel_launch(void* const* d_in, const int* in_sizes, int n_in,
                              void* d_out, int out_size, void* d_ws, size_t ws_size,
                              hipStream_t stream) {
  const float* feat = (const float*)d_in[0];
  const float* attn = (const float*)d_in[1];
  float* out = (float*)d_out;
  char* ws = (char*)d_ws;

  unsigned long long* slots = (unsigned long long*)ws;
  float* rel = (float*)(ws + 262144);
  __hip_bfloat16* H = (__hip_bfloat16*)(ws + (1 << 20));
  __hip_bfloat16* L = (__hip_bfloat16*)(ws + (1 << 20) + (8 << 20));
  float* cisT = (float*)(ws + (1 << 20) + (16 << 20));
  float* ker  = (float*)(ws + (1 << 20) + (16 << 20) + (4 << 20));

  hipMemsetAsync(d_ws, 0, 262144, stream);
  k_prep<<<1, 1024, 0, stream>>>(attn, rel);
  k_norm<<<NTOK, 256, 0, stream>>>(feat, H, L);
  k_gemm<<<dim3(32, 32), 256, 0, stream>>>(H, L, rel, ker);
  k_greedy<<<GB, GT, 0, stream>>>(ker, feat, out, cisT, slots);
}